// Round 18
// baseline (205.681 us; speedup 1.0000x reference)
//
#include <hip/hip_runtime.h>
#include <math.h>
#include <float.h>

#define PH 7
#define RLEN 32   // ints per roi in workspace

// ---- exact integer emulation of the reference's fast-math f32 binning ----
// bin = RN_f32(roi * RN_f32(1/7));  RN_f32(1/7) = 9586981 * 2^-26
#define C7 9586981LL

__device__ __forceinline__ long long round24(long long v) {
    if (v == 0) return 0;
    int L = 64 - __clzll((unsigned long long)v);
    int sh = L - 24;
    if (sh <= 0) return v;
    long long rem  = v & ((1LL << sh) - 1);
    long long base = v >> sh;
    long long half = 1LL << (sh - 1);
    if (rem > half || (rem == half && (base & 1))) base++;
    return base << sh;
}
__device__ __forceinline__ long long bin_q26(int roi) {
    return round24((long long)roi * C7);
}
__device__ __forceinline__ int floor_k(long long b26, int k) {
    long long v = round24((long long)k * b26);
    return (int)(v >> 26);
}
__device__ __forceinline__ int ceil_k(long long b26, int k) {
    long long v = round24((long long)k * b26);
    return (int)((v + ((1LL << 26) - 1)) >> 26);
}

// Per-ROI bounds (ints): [0]=b, [1..7]=hstart, [8..14]=hend,
// [15] = qs | qe<<8 (window column-quad range), [16..22]=ws, [23..29]=we
__global__ void roi_bounds_kernel(const float* __restrict__ rois,
                                  int* __restrict__ wsbuf, int R) {
    int r = blockIdx.x * blockDim.x + threadIdx.x;
    if (r >= R) return;
    const int H = 64, W = 64;
    const float* roi = rois + r * 5;
    int b  = (int)roi[0];
    int x1 = (int)rintf(roi[1] * 0.0625f);
    int y1 = (int)rintf(roi[2] * 0.0625f);
    int x2 = (int)rintf(roi[3] * 0.0625f);
    int y2 = (int)rintf(roi[4] * 0.0625f);

    int roi_w = max(x2 - x1 + 1, 1);
    int roi_h = max(y2 - y1 + 1, 1);
    long long bh = bin_q26(roi_h);
    long long bw = bin_q26(roi_w);

    int* o = wsbuf + r * RLEN;
    o[0] = b;
    int ws0 = 64, we6 = 0;
    #pragma unroll
    for (int i = 0; i < PH; ++i) {
        int hs = min(max(y1 + floor_k(bh, i),     0), H);
        int he = min(max(y1 + ceil_k (bh, i + 1), 0), H);
        int wst = min(max(x1 + floor_k(bw, i),     0), W);
        int wen = min(max(x1 + ceil_k (bw, i + 1), 0), W);
        o[1 + i]  = hs;
        o[8 + i]  = he;
        o[16 + i] = wst;
        o[23 + i] = wen;
        if (i == 0) ws0 = wst;
        if (i == 6) we6 = wen;
    }
    int qs = ws0 >> 2;
    int qe = (we6 + 3) >> 2;
    o[15] = qs | (max(qe, qs) << 8);
}

__device__ __forceinline__ float4 max4(float4 a, float4 b) {
    float4 r;
    r.x = fmaxf(a.x, b.x); r.y = fmaxf(a.y, b.y);
    r.z = fmaxf(a.z, b.z); r.w = fmaxf(a.w, b.w);
    return r;
}

// One wave = 8 channels of one roi. lane = chsub*8 + cq8.
// R17 base (row carry, dual-tile single pass, double-buffered cm + lagged
// reduce) + CROSS-PHASE 2-ROW REGISTER PREFETCH: next phase's first two rows
// are issued before the lagged reduce, so phase transitions become register
// handoffs (avg bin height 3.1 rows -> prefetch covers most phases fully).
// Block = 256 threads = 4 independent waves (no barriers). Grid = R * 16.
__global__ __launch_bounds__(256) void roipool_main(
        const float* __restrict__ features,
        const int* __restrict__ wsbuf,
        float* __restrict__ out) {
    __shared__ float cmA[4][8][68];   // 8704 B
    __shared__ float cmB[4][8][68];   // 8704 B

    int r    = blockIdx.x >> 4;      // 16 blocks per roi (32 ch each)
    int cg   = blockIdx.x & 15;
    int wv   = threadIdx.x >> 6;
    int lane = threadIdx.x & 63;
    int chsub = lane >> 3;           // 0..7: channel within wave
    int cq8   = lane & 7;            // quad slot within tile
    int c0   = (cg << 5) + (wv << 3);

    const int* B = wsbuf + r * RLEN; // wave-uniform -> scalar loads
    int b   = B[0];
    int qpk = B[15];
    int qs  = qpk & 255;
    int qe  = qpk >> 8;
    bool dual = (qe - qs) > 8;

    const float4* f4 = (const float4*)features;
    int cbase = ((b << 9) + c0 + chsub) << 10;
    int qabs0 = qs + cq8;
    int qabs1 = qs + 8 + cq8;
    bool m0 = qabs0 < qe;
    bool m1 = qabs1 < qe;
    int qc1 = min(qabs1, 15);        // clamped (dual tile1 only)

    // epilogue lane mapping (8 ch * 7 pw = 56 active lanes)
    int ech = (lane * 9363) >> 16;   // lane/7 for lane<56
    int epw = lane - ech * 7;
    int ews = B[16 + epw];           // per-lane, L1-hot
    int ewe = B[23 + epw];
    bool eact = lane < 56;
    const float* erowA = cmA[wv][ech & 7];
    const float* erowB = cmB[wv][ech & 7];
    float vals[PH];
    int phs = 0, phe = 0;            // previous phase h-bounds (for lag)

    const float4 NEG4 = make_float4(-FLT_MAX, -FLT_MAX, -FLT_MAX, -FLT_MAX);
    float4 last0 = NEG4, last1 = NEG4;   // final-row carry
    int last_h = -100;

    if (!dual) {
        float4 pre0 = NEG4, pre1 = NEG4;
        if (m0) {                         // initial prefetch: rows hs[0], hs[0]+1
            int r0 = min(B[1], 63);
            int r1 = min(B[1] + 1, 63);
            pre0 = f4[cbase + (r0 << 4) + qabs0];
            pre1 = f4[cbase + (r1 << 4) + qabs0];
        }
        #pragma unroll
        for (int ph = 0; ph < PH; ++ph) {
            int hs = B[1 + ph], he = B[8 + ph];   // wave-uniform scalars
            float (*cw)[68] = (ph & 1) ? cmB[wv] : cmA[wv];
            if (m0) {
                if (he > hs) {
                    bool reuse = (hs == last_h);
                    float4 a0 = reuse ? last0 : NEG4;
                    int h0 = hs + (reuse ? 1 : 0);
                    int cnt = he - h0;            // rows to load: h0..he-1
                    if (cnt > 0) {
                        a0 = max4(a0, pre0);      // row h0 (prefetched)
                        float4 lc0 = pre0;
                        if (cnt >= 2) { a0 = max4(a0, pre1); lc0 = pre1; }
                        if (cnt >= 3) {
                            int nbody = cnt - 3;  // rows h0+2 .. he-2
                            int idx = cbase + ((h0 + 2) << 4) + qabs0;
                            while (nbody >= 4) {  // 4 loads in flight
                                float4 v0 = f4[idx];
                                float4 v1 = f4[idx + 16];
                                float4 v2 = f4[idx + 32];
                                float4 v3 = f4[idx + 48];
                                a0 = max4(a0, max4(max4(v0, v1), max4(v2, v3)));
                                idx += 64; nbody -= 4;
                            }
                            if (nbody >= 2) {
                                float4 v0 = f4[idx];
                                float4 v1 = f4[idx + 16];
                                a0 = max4(a0, max4(v0, v1));
                                idx += 32; nbody -= 2;
                            }
                            if (nbody >= 1) a0 = max4(a0, f4[idx]);
                            lc0 = f4[cbase + ((he - 1) << 4) + qabs0];
                            a0 = max4(a0, lc0);
                        }
                        last0 = lc0;
                        last_h = he - 1;
                    }
                    *(float4*)&cw[chsub][qabs0 << 2] = a0;
                }
                if (ph < 6) {                     // prefetch next phase's rows
                    int nhs = B[2 + ph];
                    int nh0 = nhs + ((nhs == last_h) ? 1 : 0);
                    int r0 = min(nh0, 63);
                    int r1 = min(nh0 + 1, 63);
                    pre0 = f4[cbase + (r0 << 4) + qabs0];
                    pre1 = f4[cbase + (r1 << 4) + qabs0];
                }
            }
            if (ph > 0) {                         // lagged reduce of ph-1
                const float* er = (ph & 1) ? erowA : erowB;
                float m = -FLT_MAX;
                int w = ews;
                for (; w + 2 <= ewe; w += 2)
                    m = fmaxf(fmaxf(m, er[w]), er[w + 1]);
                if (w < ewe) m = fmaxf(m, er[w]);
                vals[ph - 1] = ((phe <= phs) || (ewe <= ews)) ? 0.0f : m;
            }
            phs = hs; phe = he;
        }
    } else {
        float4 pre00, pre01, pre10, pre11;
        {
            int r0 = min(B[1], 63);
            int r1 = min(B[1] + 1, 63);
            pre00 = f4[cbase + (r0 << 4) + qabs0];
            pre01 = f4[cbase + (r1 << 4) + qabs0];
            pre10 = f4[cbase + (r0 << 4) + qc1];
            pre11 = f4[cbase + (r1 << 4) + qc1];
        }
        #pragma unroll
        for (int ph = 0; ph < PH; ++ph) {
            int hs = B[1 + ph], he = B[8 + ph];
            float (*cw)[68] = (ph & 1) ? cmB[wv] : cmA[wv];
            if (he > hs) {                        // tile0 fully active in dual
                bool reuse = (hs == last_h);
                float4 a0 = reuse ? last0 : NEG4;
                float4 a1 = reuse ? last1 : NEG4;
                int h0 = hs + (reuse ? 1 : 0);
                int cnt = he - h0;
                if (cnt > 0) {
                    a0 = max4(a0, pre00); a1 = max4(a1, pre10);
                    float4 lc0 = pre00, lc1 = pre10;
                    if (cnt >= 2) {
                        a0 = max4(a0, pre01); a1 = max4(a1, pre11);
                        lc0 = pre01; lc1 = pre11;
                    }
                    if (cnt >= 3) {
                        int nbody = cnt - 3;      // rows h0+2 .. he-2
                        int idx = cbase + ((h0 + 2) << 4);
                        while (nbody >= 2) {      // 4 loads in flight
                            float4 v00 = f4[idx + qabs0];
                            float4 v01 = f4[idx + qc1];
                            float4 v10 = f4[idx + 16 + qabs0];
                            float4 v11 = f4[idx + 16 + qc1];
                            a0 = max4(a0, max4(v00, v10));
                            a1 = max4(a1, max4(v01, v11));
                            idx += 32; nbody -= 2;
                        }
                        if (nbody >= 1) {
                            a0 = max4(a0, f4[idx + qabs0]);
                            a1 = max4(a1, f4[idx + qc1]);
                        }
                        int fin = cbase + ((he - 1) << 4);
                        lc0 = f4[fin + qabs0];
                        lc1 = f4[fin + qc1];
                        a0 = max4(a0, lc0);
                        a1 = max4(a1, lc1);
                    }
                    last0 = lc0; last1 = lc1;
                    last_h = he - 1;
                }
                *(float4*)&cw[chsub][qabs0 << 2] = a0;
                if (m1) *(float4*)&cw[chsub][qabs1 << 2] = a1;
            }
            if (ph < 6) {                         // prefetch next phase's rows
                int nhs = B[2 + ph];
                int nh0 = nhs + ((nhs == last_h) ? 1 : 0);
                int r0 = min(nh0, 63);
                int r1 = min(nh0 + 1, 63);
                pre00 = f4[cbase + (r0 << 4) + qabs0];
                pre01 = f4[cbase + (r1 << 4) + qabs0];
                pre10 = f4[cbase + (r0 << 4) + qc1];
                pre11 = f4[cbase + (r1 << 4) + qc1];
            }
            if (ph > 0) {                         // lagged reduce of ph-1
                const float* er = (ph & 1) ? erowA : erowB;
                float m = -FLT_MAX;
                int w = ews;
                for (; w + 2 <= ewe; w += 2)
                    m = fmaxf(fmaxf(m, er[w]), er[w + 1]);
                if (w < ewe) m = fmaxf(m, er[w]);
                vals[ph - 1] = ((phe <= phs) || (ewe <= ews)) ? 0.0f : m;
            }
            phs = hs; phe = he;
        }
    }
    {   // tail: reduce phase 6 (buffer 6&1 = 0 -> cmA)
        float m = -FLT_MAX;
        int w = ews;
        for (; w + 2 <= ewe; w += 2)
            m = fmaxf(fmaxf(m, erowA[w]), erowA[w + 1]);
        if (w < ewe) m = fmaxf(m, erowA[w]);
        vals[PH - 1] = ((phe <= phs) || (ewe <= ews)) ? 0.0f : m;
    }

    // stage the wave's 392 outputs (k = ech*49 + ph*7 + epw) then write
    // coalesced; cmA reuse is safe after the final reduce (wave-sync).
    float* stage = (float*)cmA[wv];
    if (eact) {
        #pragma unroll
        for (int ph = 0; ph < PH; ++ph)
            stage[ech * 49 + ph * 7 + epw] = vals[ph];
    }
    size_t obase = ((size_t)(r << 9) + c0) * 49;
    #pragma unroll
    for (int it = 0; it < 7; ++it) {
        int f = (it << 6) + lane;
        if (f < 392) out[obase + f] = stage[f];
    }
}

extern "C" void kernel_launch(void* const* d_in, const int* in_sizes, int n_in,
                              void* d_out, int out_size, void* d_ws, size_t ws_size,
                              hipStream_t stream) {
    const float* features = (const float*)d_in[0];
    const float* rois     = (const float*)d_in[1];
    float* out = (float*)d_out;
    int* wsbuf = (int*)d_ws;

    int R = in_sizes[1] / 5;   // 2000

    roi_bounds_kernel<<<(R + 255) / 256, 256, 0, stream>>>(rois, wsbuf, R);
    roipool_main<<<R * 16, 256, 0, stream>>>(features, wsbuf, out);
}